// Round 16
// baseline (151.715 us; speedup 1.0000x reference)
//
#include <hip/hip_runtime.h>

// CentroidPool: argmin_k ||x_i - c_k||^2, N=131072, K=1024, D=128, fp32.
// = argmin_k (0.5||c_k||^2 - x.c_k).
// Pass A: bf16 hi/lo 3-term split, mfma_f32_16x16x32, 32 rows/wave (grp=2),
// 128 rows/block -> 1024 blocks = 4 blocks/CU, 16 waves/CU (r15 was 8:
// per-CU matrix pipes ~13% busy, stall-bound). Live regs ~126 -> 4 w/SIMD.
// Insert uses INDEX-IN-MANTISSA packing: low 10 mantissa bits of each
// score carry k (perturbation <= 2^-8, covered by EPS2 + pass B), so
// tracking is pure fmin/med3 -- no per-value index cndmask.
// Counted-vmcnt pipeline (T3/T4) + setprio (T5) kept from r15.
// Pass B: exact fp32 recompute (coalesced coordsT), bit-identical chain.

constexpr int N = 131072;
constexpr int K = 1024;
constexpr int D = 128;
constexpr float EPS2 = 0.06f; // covers split err ~2e-3 + packing 2x4e-3

typedef __attribute__((ext_vector_type(8))) short short8;
typedef __attribute__((ext_vector_type(4))) float f32x4;

typedef const __attribute__((address_space(1))) uint* gas_uint;
typedef __attribute__((address_space(3))) uint* las_uint;

union U8 { uint4 u; short8 s; };
__device__ inline short8 as_s8(uint4 v) { U8 x; x.u = v; return x.s; }

__device__ inline uint bf16rne(float f) {
    uint u = __float_as_uint(f);
    return (u + 0x7fffu + ((u >> 16) & 1u)) >> 16;
}
__device__ inline void split2(float a, float b, uint& hi, uint& lo) {
    uint ha = bf16rne(a), hb = bf16rne(b);
    float la = a - __uint_as_float(ha << 16);
    float lb = b - __uint_as_float(hb << 16);
    hi = ha | (hb << 16);
    lo = bf16rne(la) | (bf16rne(lb) << 16);
}

// ---- prep: counter zero + 0.5*||c_k||^2 + pre-swizzled bf16 hi/lo ----
// chilo tile kt (32 k): bytes [kt*16384,+16384): hi 8K then lo 8K.
// row m, 16B-group g: offset m*256 + ((g^(m&15))<<4).
__global__ __launch_bounds__(256) void prep_kernel(
    const float* __restrict__ coords, float* __restrict__ c2half,
    uint* __restrict__ chilo, int* __restrict__ counter) {
    if (blockIdx.x == 0 && threadIdx.x == 0) counter[0] = 0;
    const int k = blockIdx.x * 4 + (threadIdx.x >> 6); // one row per wave
    const int dw = threadIdx.x & 63;
    float a = coords[k * D + 2 * dw], b = coords[k * D + 2 * dw + 1];
    uint hi, lo;
    split2(a, b, hi, lo);
    const int g = dw >> 2, sub = dw & 3, kt = k >> 5, m = k & 31;
    char* base = (char*)chilo + (size_t)kt * 16384 + m * 256 +
                 ((g ^ (m & 15)) << 4) + sub * 4;
    *(uint*)base = hi;
    *(uint*)(base + 8192) = lo;
    float s = fmaf(a, a, b * b);
#pragma unroll
    for (int off = 1; off < 64; off <<= 1) s += __shfl_xor(s, off);
    if (dw == 0) c2half[k] = 0.5f * s;
}

// ---- precompute: coordsT[d][k] = coords[k][d] (LDS-tiled, coalesced) ----
__global__ __launch_bounds__(256) void transpose_kernel(
    const float* __restrict__ coords, float* __restrict__ coordsT) {
    __shared__ float tile[64][65];
    const int k0 = blockIdx.x * 64;
    const int d0 = blockIdx.y * 64;
    const int tx = threadIdx.x & 63, ty = threadIdx.x >> 6;
#pragma unroll
    for (int i = 0; i < 64; i += 4)
        tile[ty + i][tx] = coords[(size_t)(k0 + ty + i) * D + d0 + tx];
    __syncthreads();
#pragma unroll
    for (int i = 0; i < 64; i += 4)
        coordsT[(size_t)(d0 + ty + i) * K + k0 + tx] = tile[tx][ty + i];
}

// ---- pass A: 16x16x32 MFMA, 32 rows/wave, packed-index min tracking ----
__global__ __launch_bounds__(256, 3) void centroid_mfma_kernel(
    const float* __restrict__ latent, const uint* __restrict__ chilo,
    const float* __restrict__ c2, int* __restrict__ out,
    int* __restrict__ counter, int* __restrict__ list) {
    __shared__ __align__(16) char smem[36864]; // 2 x 16K dbuf + 4K c2
    const int tid = threadIdx.x;
    const int l = tid & 63, w = tid >> 6;
    const int l15 = l & 15, l4 = l >> 4; // l4 in 0..3
    const int rowbase = blockIdx.x * 128 + w * 32;

    // B-frags: lane holds latent[rowbase + grp*16 + l15][32s + l4*8 .. +8]
    // negated, bf16 hi/lo: 2 grp x 4 s x 2 = 64 VGPRs.
    uint4 bh[2][4], bl[2][4];
#pragma unroll
    for (int grp = 0; grp < 2; ++grp) {
        const float* rp =
            latent + (size_t)(rowbase + grp * 16 + l15) * D + l4 * 8;
#pragma unroll
        for (int s = 0; s < 4; ++s) {
            float4 u = *(const float4*)(rp + 32 * s);
            float4 v = *(const float4*)(rp + 32 * s + 4);
            uint h0, o0, h1, o1, h2, o2, h3, o3;
            split2(-u.x, -u.y, h0, o0);
            split2(-u.z, -u.w, h1, o1);
            split2(-v.x, -v.y, h2, o2);
            split2(-v.z, -v.w, h3, o3);
            bh[grp][s] = make_uint4(h0, h1, h2, h3);
            bl[grp][s] = make_uint4(o0, o1, o2, o3);
        }
    }
    // c2 -> LDS (4 KB at 32768)
    *(float4*)(smem + 32768 + tid * 16) =
        *(const float4*)((const char*)c2 + tid * 16);

    // staging: wave w copies bytes [w*4096, +4096) of each 16 KB k-tile
    const int w4096 = w << 12;
    const char* gsrc0 = (const char*)chilo + w4096 + ((tid & 63) << 4);
#pragma unroll
    for (int i = 0; i < 4; ++i) // tile 0 -> buf 0
        __builtin_amdgcn_global_load_lds((gas_uint)(gsrc0 + i * 1024),
                                         (las_uint)(smem + w4096 + i * 1024),
                                         16, 0, 0);
#pragma unroll
    for (int i = 0; i < 4; ++i) // tile 1 -> buf 1
        __builtin_amdgcn_global_load_lds((gas_uint)(gsrc0 + 16384 + i * 1024),
                                         (las_uint)(smem + 16384 + w4096 + i * 1024),
                                         16, 0, 0);
    __syncthreads(); // one full drain in the prologue only

    // packed-index trackers; k rides in low 10 mantissa bits
    float m1[2] = {3.4e38f, 3.4e38f};
    float m2[2] = {3.4e38f, 3.4e38f};
    uint kpack[8]; // k for (ks,r) = ks*16 + l4*4 + r, advanced +32 per tile
#pragma unroll
    for (int ks = 0; ks < 2; ++ks)
#pragma unroll
        for (int r = 0; r < 4; ++r) kpack[ks * 4 + r] = ks * 16 + l4 * 4 + r;
    const float* c2l = (const float*)(smem + 32768);

#pragma unroll 1
    for (int t = 0; t < 32; ++t) {
        const int buf = t & 1;
        // counted wait: my 4 loads for tile t retired; t+1's stay in flight
        if (t < 31)
            asm volatile("s_waitcnt vmcnt(4)" ::: "memory");
        else
            asm volatile("s_waitcnt vmcnt(0)" ::: "memory");
        __builtin_amdgcn_s_barrier(); // all waves certified their tile-t loads
        __builtin_amdgcn_sched_barrier(0);

        const int k0 = t * 32;
        f32x4 acc[2][2]; // [ks][grp]
#pragma unroll
        for (int ks = 0; ks < 2; ++ks) {
            float4 cq = *(const float4*)(c2l + k0 + ks * 16 + l4 * 4);
#pragma unroll
            for (int grp = 0; grp < 2; ++grp) {
                acc[ks][grp][0] = cq.x;
                acc[ks][grp][1] = cq.y;
                acc[ks][grp][2] = cq.z;
                acc[ks][grp][3] = cq.w;
            }
        }

        const char* lhs = smem + buf * 16384;
        __builtin_amdgcn_s_setprio(1);
#pragma unroll
        for (int s = 0; s < 4; ++s) {
            short8 ahi[2], alo[2];
#pragma unroll
            for (int ks = 0; ks < 2; ++ks) {
                const int m = ks * 16 + l15;
                const int g = l4 + 4 * s;
                const int sw = m * 256 + ((g ^ (m & 15)) << 4);
                ahi[ks] = *(const short8*)(lhs + sw);
                alo[ks] = *(const short8*)(lhs + 8192 + sw);
            }
#pragma unroll
            for (int ks = 0; ks < 2; ++ks) {
#pragma unroll
                for (int grp = 0; grp < 2; ++grp) {
                    acc[ks][grp] = __builtin_amdgcn_mfma_f32_16x16x32_bf16(
                        ahi[ks], as_s8(bh[grp][s]), acc[ks][grp], 0, 0, 0);
                    acc[ks][grp] = __builtin_amdgcn_mfma_f32_16x16x32_bf16(
                        ahi[ks], as_s8(bl[grp][s]), acc[ks][grp], 0, 0, 0);
                    acc[ks][grp] = __builtin_amdgcn_mfma_f32_16x16x32_bf16(
                        alo[ks], as_s8(bh[grp][s]), acc[ks][grp], 0, 0, 0);
                }
            }
        }
        __builtin_amdgcn_s_setprio(0);
        __builtin_amdgcn_sched_barrier(0);

        // insert: pack k into low 10 mantissa bits, then min/med3 only
#pragma unroll
        for (int ks = 0; ks < 2; ++ks) {
#pragma unroll
            for (int r = 0; r < 4; ++r) {
                const uint kk = kpack[ks * 4 + r];
#pragma unroll
                for (int grp = 0; grp < 2; ++grp) {
                    uint pb = (__float_as_uint(acc[ks][grp][r]) & 0xFFFFFC00u) | kk;
                    float vp = __uint_as_float(pb);
                    m2[grp] = __builtin_amdgcn_fmed3f(vp, m1[grp], m2[grp]);
                    m1[grp] = fminf(m1[grp], vp);
                }
            }
        }
#pragma unroll
        for (int i = 0; i < 8; ++i) kpack[i] += 32;

        __builtin_amdgcn_s_barrier(); // all waves done reading buf[t&1]
        __builtin_amdgcn_sched_barrier(0);
        if (t < 30) { // issue tile t+2 into the buffer just freed
            const char* gs = gsrc0 + (size_t)(t + 2) * 16384;
            char* ls = smem + buf * 16384 + w4096;
#pragma unroll
            for (int i = 0; i < 4; ++i)
                __builtin_amdgcn_global_load_lds((gas_uint)(gs + i * 1024),
                                                 (las_uint)(ls + i * 1024),
                                                 16, 0, 0);
        }
    }

    // merge k-partitions: lanes l, l^16, l^32, l^48 hold same rows (l15)
#pragma unroll
    for (int off = 16; off <= 32; off <<= 1) {
#pragma unroll
        for (int grp = 0; grp < 2; ++grp) {
            float om = __shfl_xor(m1[grp], off);
            float o2 = __shfl_xor(m2[grp], off);
            m2[grp] = fminf(fminf(m2[grp], o2), fmaxf(m1[grp], om));
            m1[grp] = fminf(m1[grp], om);
        }
    }

    // lanes 0..15 own rows rowbase + grp*16 + l
    bool flg[2];
    unsigned long long bm[2];
    int total = 0;
#pragma unroll
    for (int grp = 0; grp < 2; ++grp) {
        flg[grp] = (l < 16) && ((m2[grp] - m1[grp]) <= EPS2);
        bm[grp] = __ballot(flg[grp]);
        total += __popcll(bm[grp]);
    }
    int pos = 0;
    if (l == 0 && total) pos = atomicAdd(counter, total);
    pos = __shfl(pos, 0);
    if (l < 16) {
        int run = pos;
#pragma unroll
        for (int grp = 0; grp < 2; ++grp) {
            out[rowbase + grp * 16 + l] = (int)(__float_as_uint(m1[grp]) & 1023u);
            if (flg[grp])
                list[run + __popcll(bm[grp] & ((1ull << l) - 1ull))] =
                    rowbase + grp * 16 + l;
            run += __popcll(bm[grp]);
        }
    }
}

// ---- pass B: exact fp32 recompute, 4 rows/wave-task, coalesced coordsT ----
__global__ __launch_bounds__(256) void centroid_exact_kernel(
    const float* __restrict__ latent, const float* __restrict__ coordsT,
    const float* __restrict__ c2, const int* __restrict__ cnt_list,
    int* __restrict__ out) {
    const int count = cnt_list[0];
    const int* list = cnt_list + 16;
    const int lane = threadIdx.x & 63;
    const int gw = (blockIdx.x * 256 + threadIdx.x) >> 6;
    const int nwaves = gridDim.x * 4;
    // lane owns k = c*64 + lane, c = 0..15 (coalesced coordsT reads)

    for (int task = gw; task * 4 < count; task += nwaves) {
        const int base = task * 4;
        const int nr = min(4, count - base);
        const float* xp[4];
        int rows[4];
#pragma unroll
        for (int j = 0; j < 4; ++j) {
            int idx = base + (j < nr ? j : nr - 1);
            rows[j] = __builtin_amdgcn_readfirstlane(list[idx]);
            xp[j] = latent + (size_t)rows[j] * D;
        }

        float acc[16][4];
#pragma unroll
        for (int c = 0; c < 16; ++c) {
            float cc = c2[c * 64 + lane];
#pragma unroll
            for (int j = 0; j < 4; ++j) acc[c][j] = cc;
        }

#pragma unroll 1
        for (int d4 = 0; d4 < D / 4; ++d4) {
            float4 xq[4];
#pragma unroll
            for (int j = 0; j < 4; ++j)
                xq[j] = *(const float4*)(xp[j] + 4 * d4);
            float ct[4][16];
#pragma unroll
            for (int dd = 0; dd < 4; ++dd)
#pragma unroll
                for (int c = 0; c < 16; ++c)
                    ct[dd][c] = coordsT[(size_t)(4 * d4 + dd) * K + c * 64 + lane];
#pragma unroll
            for (int dd = 0; dd < 4; ++dd) {
#pragma unroll
                for (int c = 0; c < 16; ++c) {
#pragma unroll
                    for (int j = 0; j < 4; ++j) {
                        float xv = (dd == 0) ? xq[j].x
                                 : (dd == 1) ? xq[j].y
                                 : (dd == 2) ? xq[j].z : xq[j].w;
                        acc[c][j] = fmaf(-xv, ct[dd][c], acc[c][j]);
                    }
                }
            }
        }

#pragma unroll
        for (int j = 0; j < 4; ++j) {
            float m1 = acc[0][j];
            int i1 = lane;
#pragma unroll
            for (int c = 1; c < 16; ++c) {
                const int kk = c * 64 + lane;
                if (acc[c][j] < m1) { m1 = acc[c][j]; i1 = kk; }
            }
#pragma unroll
            for (int off = 1; off < 64; off <<= 1) {
                float om = __shfl_xor(m1, off);
                int oi = __shfl_xor(i1, off);
                if (om < m1 || (om == m1 && oi < i1)) { m1 = om; i1 = oi; }
            }
            if (lane == 0 && j < nr) out[rows[j]] = i1;
        }
    }
}

extern "C" void kernel_launch(void* const* d_in, const int* in_sizes, int n_in,
                              void* d_out, int out_size, void* d_ws, size_t ws_size,
                              hipStream_t stream) {
    const float* latent = (const float*)d_in[0];
    const float* coords = (const float*)d_in[1];
    int* out = (int*)d_out;

    char* ws = (char*)d_ws;
    size_t off = 0;
    float* c2 = (float*)(ws + off); off += 4096;
    uint* chilo = (uint*)(ws + off); off += 524288;     // pre-swizzled hi/lo
    float* coordsT = (float*)(ws + off); off += 524288;
    int* cnt_list = (int*)(ws + off); off += 64 + 524288;
    int* counter = cnt_list;
    int* list = cnt_list + 16;

    prep_kernel<<<K / 4, 256, 0, stream>>>(coords, c2, chilo, counter);
    {
        dim3 g(K / 64, D / 64);
        transpose_kernel<<<g, 256, 0, stream>>>(coords, coordsT);
    }
    // 128 rows/block, full K: 1024 blocks = 4 blocks/CU, 16 waves/CU
    centroid_mfma_kernel<<<N / 128, 256, 0, stream>>>(latent, chilo, c2, out,
                                                      counter, list);
    centroid_exact_kernel<<<2048, 256, 0, stream>>>(latent, coordsT, c2,
                                                    cnt_list, out);
}